// Round 4
// baseline (354.222 us; speedup 1.0000x reference)
//
#include <hip/hip_runtime.h>
#include <stddef.h>
#include <stdint.h>

#define B_   32
#define IN_  4096
#define OUT_ 14336

typedef short v8s __attribute__((ext_vector_type(8)));
typedef float v4f __attribute__((ext_vector_type(4)));
typedef int   v4i __attribute__((ext_vector_type(4)));

__device__ __constant__ float c_nf4[16] = {
    -1.0f, -0.6961928009986877f, -0.5250730514526367f, -0.39491748809814453f,
    -0.28444138169288635f, -0.18477343022823334f, -0.09105003625154495f, 0.0f,
    0.07958029955625534f, 0.16093020141124725f, 0.24611230194568634f,
    0.33791524171829224f, 0.44070982933044434f, 0.5626170039176941f,
    0.7229568362236023f, 1.0f};

__device__ __forceinline__ unsigned f2bf_u(float f) {
    union { float f; unsigned u; } v; v.f = f;
    return (v.u + 0x7FFFu + ((v.u >> 16) & 1u)) >> 16;   // RNE, no NaN inputs
}
__device__ __forceinline__ unsigned pack2(float lo, float hi) {
    return f2bf_u(lo) | (f2bf_u(hi) << 16);
}

// x[32][4096] f32 -> xB bf16 in B-fragment layout for mfma_f32_16x16x32_bf16.
// Fragment t = (kt*2 + bt)*64 + l holds B[k = kt*32 + (l>>4)*8 + j][n = bt*16 + (l&15)]
__global__ __launch_bounds__(256) void prep(const float* __restrict__ x,
                                            unsigned* __restrict__ xB) {
    int t  = blockIdx.x * 256 + threadIdx.x;   // 0..16383
    int kt = t >> 7;
    int bt = (t >> 6) & 1;
    int l  = t & 63;
    int b  = bt * 16 + (l & 15);
    int k0 = kt * 32 + (l >> 4) * 8;
    const float* xr = x + (size_t)b * IN_ + k0;
    float4 a = *(const float4*)xr;
    float4 c = *(const float4*)(xr + 4);
    uint4 w;
    w.x = pack2(a.x, a.y);
    w.y = pack2(a.z, a.w);
    w.z = pack2(c.x, c.y);
    w.w = pack2(c.z, c.w);
    *(uint4*)(xB + (size_t)t * 4) = w;
}

// out[b][o] = bias[o]  (pre-init so split-K blocks can pure-atomicAdd)
__global__ __launch_bounds__(256) void init_out(const float* __restrict__ bias,
                                                float* __restrict__ out) {
    int t   = blockIdx.x * 256 + threadIdx.x;
    int o   = (t * 4) % OUT_;
    int row = (t * 4) / OUT_;
    float4 bv = *(const float4*)(bias + o);
    *(float4*)(out + (size_t)row * OUT_ + o) = bv;
}

// codes[OUT][4096] int32 (0..15) -> pk[OUT][512] dwords, 8 codes/dword
// (nibble i at bit 4i, so each BYTE = pair-LUT index for 2 consecutive k).
// Within each row's 128-dword kq-block, dwords are permuted so the mfma
// kernel's lane (q) reads one aligned uint4 per kbp:
//   src K8 = kq*128 + kb*8 + s*4 + q  ->  dst = kq*128 + (kb>>1)*16 + q*4 + (kb&1)*2 + s
// Reads perfectly coalesced (32 B/thread, consecutive); writes land as a
// permutation within complete 256 B windows per wave (full-line coverage).
__global__ __launch_bounds__(256) void pack_codes(const int* __restrict__ codes,
                                                  unsigned* __restrict__ pk) {
    const size_t total = (size_t)OUT_ * 512;
    size_t t = (size_t)blockIdx.x * 256 + threadIdx.x;
    for (; t < total; t += (size_t)gridDim.x * 256) {
        const v4i* src = (const v4i*)(codes + t * 8);
        v4i a = __builtin_nontemporal_load(src);
        v4i b = __builtin_nontemporal_load(src + 1);
        unsigned d = (unsigned)(a.x & 15)        | ((unsigned)(a.y & 15) << 4)  |
                     ((unsigned)(a.z & 15) << 8)  | ((unsigned)(a.w & 15) << 12) |
                     ((unsigned)(b.x & 15) << 16) | ((unsigned)(b.y & 15) << 20) |
                     ((unsigned)(b.z & 15) << 24) | ((unsigned)(b.w & 15) << 28);
        unsigned K8 = (unsigned)(t & 511);
        unsigned kq = K8 >> 7, r = K8 & 127;
        unsigned kb = r >> 3, s = (r >> 2) & 1, q = r & 3;
        unsigned pidx = kq * 128 + (kb >> 1) * 16 + q * 4 + (kb & 1) * 2 + s;
        pk[(t & ~(size_t)511) + pidx] = d;
    }
}

// Grid (224, 4) x 256. Wave w of block (bx,kq): o-rows [bx*64 + w*16, +16),
// k in [kq*1024, +1024).  Codes come pre-packed (pk): one uint4 per lane per
// kbp = 2 absmax-blocks; each byte is a 256-entry pair-LUT index (unscaled
// bf16 pairs). Per-64k-block absmax applied to the MFMA partial accumulator
// (D-row == A-row == output feature), folded with 8 FMAs/block. Partials
// atomicAdd'ed into bias-pre-initialized out.
__global__ __launch_bounds__(256) void nf4_mfma(
    const unsigned* __restrict__ pk, const float* __restrict__ absmax,
    const unsigned* __restrict__ xB, float* __restrict__ out) {
    __shared__ unsigned plut[256];
    plut[threadIdx.x] = pack2(c_nf4[threadIdx.x & 15], c_nf4[threadIdx.x >> 4]);
    __syncthreads();

    const int w  = threadIdx.x >> 6;
    const int l  = threadIdx.x & 63;
    const int o0 = blockIdx.x * 64 + w * 16;
    const int kq = blockIdx.y;                 // 0..3
    const int m  = l & 15;
    const int q  = l >> 4;

    const unsigned* prow = pk + (size_t)(o0 + m) * 512 + kq * 128 + q * 4;
    const uint4*    xbp  = (const uint4*)xB + l + (size_t)(kq * 32) * 128;
    const float*    amp  = absmax + (size_t)(o0 + q * 4) * 64 + kq * 16;

    v4f main0 = {0.f, 0.f, 0.f, 0.f};
    v4f main1 = {0.f, 0.f, 0.f, 0.f};
    const v4f zro = {0.f, 0.f, 0.f, 0.f};

#pragma unroll 2
    for (int kbp = 0; kbp < 8; ++kbp) {        // 2 absmax-blocks (128 k) per iter
        uint4 pkv = *(const uint4*)(prow + kbp * 16);
        const int kb0 = kbp * 2, kb1 = kbp * 2 + 1;
        uint4 b0 = xbp[(size_t)kb0 * 256];        // kb0 step0, b-tile 0
        uint4 b1 = xbp[(size_t)kb0 * 256 + 64];   // kb0 step0, b-tile 1
        uint4 b2 = xbp[(size_t)kb0 * 256 + 128];  // kb0 step1, b-tile 0
        uint4 b3 = xbp[(size_t)kb0 * 256 + 192];  // kb0 step1, b-tile 1
        uint4 b4 = xbp[(size_t)kb1 * 256];
        uint4 b5 = xbp[(size_t)kb1 * 256 + 64];
        uint4 b6 = xbp[(size_t)kb1 * 256 + 128];
        uint4 b7 = xbp[(size_t)kb1 * 256 + 192];
        float am00 = amp[kb0],       am01 = amp[kb0 + 64];
        float am02 = amp[kb0 + 128], am03 = amp[kb0 + 192];
        float am10 = amp[kb1],       am11 = amp[kb1 + 64];
        float am12 = amp[kb1 + 128], am13 = amp[kb1 + 192];

        union { uint4 u; v8s v; } aA, aB, f0, f1, f2, f3;

        // ---- absmax block kb0: dwords pkv.x (step0), pkv.y (step1) ----
        aA.u.x = plut[pkv.x & 0xff];         aA.u.y = plut[(pkv.x >> 8) & 0xff];
        aA.u.z = plut[(pkv.x >> 16) & 0xff]; aA.u.w = plut[pkv.x >> 24];
        aB.u.x = plut[pkv.y & 0xff];         aB.u.y = plut[(pkv.y >> 8) & 0xff];
        aB.u.z = plut[(pkv.y >> 16) & 0xff]; aB.u.w = plut[pkv.y >> 24];
        f0.u = b0; f1.u = b1; f2.u = b2; f3.u = b3;
        {
            v4f blk0 = __builtin_amdgcn_mfma_f32_16x16x32_bf16(aA.v, f0.v, zro, 0, 0, 0);
            v4f blk1 = __builtin_amdgcn_mfma_f32_16x16x32_bf16(aA.v, f1.v, zro, 0, 0, 0);
            blk0 = __builtin_amdgcn_mfma_f32_16x16x32_bf16(aB.v, f2.v, blk0, 0, 0, 0);
            blk1 = __builtin_amdgcn_mfma_f32_16x16x32_bf16(aB.v, f3.v, blk1, 0, 0, 0);
            main0[0] += am00 * blk0[0];  main1[0] += am00 * blk1[0];
            main0[1] += am01 * blk0[1];  main1[1] += am01 * blk1[1];
            main0[2] += am02 * blk0[2];  main1[2] += am02 * blk1[2];
            main0[3] += am03 * blk0[3];  main1[3] += am03 * blk1[3];
        }

        // ---- absmax block kb1: dwords pkv.z (step0), pkv.w (step1) ----
        aA.u.x = plut[pkv.z & 0xff];         aA.u.y = plut[(pkv.z >> 8) & 0xff];
        aA.u.z = plut[(pkv.z >> 16) & 0xff]; aA.u.w = plut[pkv.z >> 24];
        aB.u.x = plut[pkv.w & 0xff];         aB.u.y = plut[(pkv.w >> 8) & 0xff];
        aB.u.z = plut[(pkv.w >> 16) & 0xff]; aB.u.w = plut[pkv.w >> 24];
        f0.u = b4; f1.u = b5; f2.u = b6; f3.u = b7;
        {
            v4f blk0 = __builtin_amdgcn_mfma_f32_16x16x32_bf16(aA.v, f0.v, zro, 0, 0, 0);
            v4f blk1 = __builtin_amdgcn_mfma_f32_16x16x32_bf16(aA.v, f1.v, zro, 0, 0, 0);
            blk0 = __builtin_amdgcn_mfma_f32_16x16x32_bf16(aB.v, f2.v, blk0, 0, 0, 0);
            blk1 = __builtin_amdgcn_mfma_f32_16x16x32_bf16(aB.v, f3.v, blk1, 0, 0, 0);
            main0[0] += am10 * blk0[0];  main1[0] += am10 * blk1[0];
            main0[1] += am11 * blk0[1];  main1[1] += am11 * blk1[1];
            main0[2] += am12 * blk0[2];  main1[2] += am12 * blk1[2];
            main0[3] += am13 * blk0[3];  main1[3] += am13 * blk1[3];
        }
    }

    // D layout: col = l&15 (= batch b within tile), row = q*4 + r (= o offset)
    const int bc = l & 15;
    const int ob = o0 + q * 4;
#pragma unroll
    for (int r = 0; r < 4; ++r) {
        atomicAdd(&out[(size_t)bc * OUT_ + ob + r],        main0[r]);
        atomicAdd(&out[(size_t)(bc + 16) * OUT_ + ob + r], main1[r]);
    }
}

extern "C" void kernel_launch(void* const* d_in, const int* in_sizes, int n_in,
                              void* d_out, int out_size, void* d_ws, size_t ws_size,
                              hipStream_t stream) {
    const float* x      = (const float*)d_in[0];
    const int*   codes  = (const int*)d_in[1];
    const float* absmax = (const float*)d_in[2];
    const float* bias   = (const float*)d_in[3];
    float* out = (float*)d_out;
    unsigned* xB = (unsigned*)d_ws;                          // 256 KB
    unsigned* pk = (unsigned*)((char*)d_ws + (1u << 20));    // 29.4 MB packed codes

    pack_codes<<<dim3(2048), 256, 0, stream>>>(codes, pk);
    init_out<<<dim3(448), 256, 0, stream>>>(bias, out);
    prep<<<dim3(64), 256, 0, stream>>>(x, xB);
    nf4_mfma<<<dim3(OUT_ / 64, 4), 256, 0, stream>>>(pk, absmax, xB, out);
}

// Round 5
// 336.979 us; speedup vs baseline: 1.0512x; 1.0512x over previous
//
#include <hip/hip_runtime.h>
#include <stddef.h>
#include <stdint.h>

#define B_   32
#define IN_  4096
#define OUT_ 14336

typedef short v8s __attribute__((ext_vector_type(8)));
typedef float v4f __attribute__((ext_vector_type(4)));
typedef int   v4i __attribute__((ext_vector_type(4)));

__device__ __constant__ float c_nf4[16] = {
    -1.0f, -0.6961928009986877f, -0.5250730514526367f, -0.39491748809814453f,
    -0.28444138169288635f, -0.18477343022823334f, -0.09105003625154495f, 0.0f,
    0.07958029955625534f, 0.16093020141124725f, 0.24611230194568634f,
    0.33791524171829224f, 0.44070982933044434f, 0.5626170039176941f,
    0.7229568362236023f, 1.0f};

__device__ __forceinline__ unsigned f2bf_u(float f) {
    union { float f; unsigned u; } v; v.f = f;
    return (v.u + 0x7FFFu + ((v.u >> 16) & 1u)) >> 16;   // RNE, no NaN inputs
}
__device__ __forceinline__ unsigned pack2(float lo, float hi) {
    return f2bf_u(lo) | (f2bf_u(hi) << 16);
}

// x[32][4096] f32 -> xB bf16 in B-fragment layout for mfma_f32_16x16x32_bf16.
// Fragment t = (kt*2 + bt)*64 + l holds B[k = kt*32 + (l>>4)*8 + j][n = bt*16 + (l&15)]
__global__ __launch_bounds__(256) void prep(const float* __restrict__ x,
                                            unsigned* __restrict__ xB) {
    int t  = blockIdx.x * 256 + threadIdx.x;   // 0..16383
    int kt = t >> 7;
    int bt = (t >> 6) & 1;
    int l  = t & 63;
    int b  = bt * 16 + (l & 15);
    int k0 = kt * 32 + (l >> 4) * 8;
    const float* xr = x + (size_t)b * IN_ + k0;
    float4 a = *(const float4*)xr;
    float4 c = *(const float4*)(xr + 4);
    uint4 w;
    w.x = pack2(a.x, a.y);
    w.y = pack2(a.z, a.w);
    w.z = pack2(c.x, c.y);
    w.w = pack2(c.z, c.w);
    *(uint4*)(xB + (size_t)t * 4) = w;
}

// Grid 448 x 512 (8 waves). Block bx: o-rows [bx*32, +32).
// Wave w: ot = w&1 (16-row subtile), ks = w>>1 (K quarter, 1024 k each).
// Dequant: direct nontemporal code loads, 256-entry pair-LUT (unscaled bf16
// pairs), per-64k absmax applied to the per-block MFMA partial accumulator
// (D-row == A-row == output feature), folded with 4 FMAs/block per acc.
// K-partials combined through LDS; bias applied at the final store.
// No atomics, no extra global passes.
__global__ __launch_bounds__(512, 4) void nf4_mfma(
    const int* __restrict__ codes, const float* __restrict__ absmax,
    const unsigned* __restrict__ xB, const float* __restrict__ bias,
    float* __restrict__ out) {
    __shared__ unsigned plut[256];
    __shared__ float red[4][32][33];           // [ks][o-row][batch], padded
    if (threadIdx.x < 256)
        plut[threadIdx.x] = pack2(c_nf4[threadIdx.x & 15], c_nf4[threadIdx.x >> 4]);
    __syncthreads();

    const int w  = threadIdx.x >> 6;
    const int l  = threadIdx.x & 63;
    const int ot = w & 1;
    const int ks = w >> 1;                     // 0..3
    const int o0 = blockIdx.x * 32 + ot * 16;
    const int m  = l & 15;
    const int q  = l >> 4;

    const int*   crow = codes + (size_t)(o0 + m) * IN_ + (size_t)ks * 1024 + q * 8;
    const uint4* xbp  = (const uint4*)xB + l + (size_t)(ks * 32) * 128;
    const float* amp  = absmax + (size_t)(o0 + q * 4) * 64 + ks * 16;

    v4f main0 = {0.f, 0.f, 0.f, 0.f};
    v4f main1 = {0.f, 0.f, 0.f, 0.f};
    const v4f zro = {0.f, 0.f, 0.f, 0.f};

    for (int kb = 0; kb < 16; ++kb) {          // one 64-k absmax block per iter
        const int* cA = crow + kb * 64;
        v4i c0 = __builtin_nontemporal_load((const v4i*)(cA));       // step A
        v4i c1 = __builtin_nontemporal_load((const v4i*)(cA + 4));
        v4i c2 = __builtin_nontemporal_load((const v4i*)(cA + 32));  // step B
        v4i c3 = __builtin_nontemporal_load((const v4i*)(cA + 36));
        uint4 b0 = xbp[(size_t)kb * 256];        // step A, b-tile 0
        uint4 b1 = xbp[(size_t)kb * 256 + 64];   // step A, b-tile 1
        uint4 b2 = xbp[(size_t)kb * 256 + 128];  // step B, b-tile 0
        uint4 b3 = xbp[(size_t)kb * 256 + 192];  // step B, b-tile 1
        float am0 = amp[kb];
        float am1 = amp[kb + 64];
        float am2 = amp[kb + 128];
        float am3 = amp[kb + 192];

        union { uint4 u; v8s v; } aA, aB, f0, f1, f2, f3;
        aA.u.x = plut[c0.x | (c0.y << 4)];
        aA.u.y = plut[c0.z | (c0.w << 4)];
        aA.u.z = plut[c1.x | (c1.y << 4)];
        aA.u.w = plut[c1.z | (c1.w << 4)];
        aB.u.x = plut[c2.x | (c2.y << 4)];
        aB.u.y = plut[c2.z | (c2.w << 4)];
        aB.u.z = plut[c3.x | (c3.y << 4)];
        aB.u.w = plut[c3.z | (c3.w << 4)];
        f0.u = b0; f1.u = b1; f2.u = b2; f3.u = b3;

        v4f blk0 = __builtin_amdgcn_mfma_f32_16x16x32_bf16(aA.v, f0.v, zro, 0, 0, 0);
        v4f blk1 = __builtin_amdgcn_mfma_f32_16x16x32_bf16(aA.v, f1.v, zro, 0, 0, 0);
        blk0 = __builtin_amdgcn_mfma_f32_16x16x32_bf16(aB.v, f2.v, blk0, 0, 0, 0);
        blk1 = __builtin_amdgcn_mfma_f32_16x16x32_bf16(aB.v, f3.v, blk1, 0, 0, 0);

        main0[0] += am0 * blk0[0];  main1[0] += am0 * blk1[0];
        main0[1] += am1 * blk0[1];  main1[1] += am1 * blk1[1];
        main0[2] += am2 * blk0[2];  main1[2] += am2 * blk1[2];
        main0[3] += am3 * blk0[3];  main1[3] += am3 * blk1[3];
    }

    // Partials -> LDS. D layout: col = l&15 (= batch), row = q*4 + r (= o off).
    const int rr = ot * 16 + q * 4;
#pragma unroll
    for (int r = 0; r < 4; ++r) {
        red[ks][rr + r][m]      = main0[r];
        red[ks][rr + r][m + 16] = main1[r];
    }
    __syncthreads();

    // Combine 4 K-quarters + bias, store coalesced (float2 per thread).
    const int c  = threadIdx.x >> 4;           // batch 0..31
    const int r2 = (threadIdx.x & 15) * 2;     // o-row offset, even
    const int o  = blockIdx.x * 32 + r2;
    float s0 = red[0][r2][c] + red[1][r2][c] + red[2][r2][c] + red[3][r2][c]
             + bias[o];
    float s1 = red[0][r2 + 1][c] + red[1][r2 + 1][c] + red[2][r2 + 1][c]
             + red[3][r2 + 1][c] + bias[o + 1];
    float2 st = {s0, s1};
    *(float2*)(out + (size_t)c * OUT_ + o) = st;
}

extern "C" void kernel_launch(void* const* d_in, const int* in_sizes, int n_in,
                              void* d_out, int out_size, void* d_ws, size_t ws_size,
                              hipStream_t stream) {
    const float* x      = (const float*)d_in[0];
    const int*   codes  = (const int*)d_in[1];
    const float* absmax = (const float*)d_in[2];
    const float* bias   = (const float*)d_in[3];
    float* out = (float*)d_out;
    unsigned* xB = (unsigned*)d_ws;   // 256 KB

    prep<<<dim3(64), 256, 0, stream>>>(x, xB);
    nf4_mfma<<<dim3(OUT_ / 32), 512, 0, stream>>>(codes, absmax, xB, bias, out);
}

// Round 7
// 333.736 us; speedup vs baseline: 1.0614x; 1.0097x over previous
//
#include <hip/hip_runtime.h>
#include <stddef.h>
#include <stdint.h>

#define B_   32
#define IN_  4096
#define OUT_ 14336

typedef short v8s __attribute__((ext_vector_type(8)));
typedef float v4f __attribute__((ext_vector_type(4)));
typedef int   v4i __attribute__((ext_vector_type(4)));

__device__ __constant__ float c_nf4[16] = {
    -1.0f, -0.6961928009986877f, -0.5250730514526367f, -0.39491748809814453f,
    -0.28444138169288635f, -0.18477343022823334f, -0.09105003625154495f, 0.0f,
    0.07958029955625534f, 0.16093020141124725f, 0.24611230194568634f,
    0.33791524171829224f, 0.44070982933044434f, 0.5626170039176941f,
    0.7229568362236023f, 1.0f};

__device__ __forceinline__ unsigned f2bf_u(float f) {
    union { float f; unsigned u; } v; v.f = f;
    return (v.u + 0x7FFFu + ((v.u >> 16) & 1u)) >> 16;   // RNE, no NaN inputs
}
__device__ __forceinline__ unsigned pack2(float lo, float hi) {
    return f2bf_u(lo) | (f2bf_u(hi) << 16);
}

// x[32][4096] f32 -> xB bf16 in B-fragment layout for mfma_f32_16x16x32_bf16.
// Fragment t = (kt*2 + bt)*64 + l holds B[k = kt*32 + (l>>4)*8 + j][n = bt*16 + (l&15)]
__global__ __launch_bounds__(256) void prep(const float* __restrict__ x,
                                            unsigned* __restrict__ xB) {
    int t  = blockIdx.x * 256 + threadIdx.x;   // 0..16383
    int kt = t >> 7;
    int bt = (t >> 6) & 1;
    int l  = t & 63;
    int b  = bt * 16 + (l & 15);
    int k0 = kt * 32 + (l >> 4) * 8;
    const float* xr = x + (size_t)b * IN_ + k0;
    float4 a = *(const float4*)xr;
    float4 c = *(const float4*)(xr + 4);
    uint4 w;
    w.x = pack2(a.x, a.y);
    w.y = pack2(a.z, a.w);
    w.z = pack2(c.x, c.y);
    w.w = pack2(c.z, c.w);
    *(uint4*)(xB + (size_t)t * 4) = w;
}

// Grid 224 x 256 (4 waves). Wave w: o-tile [blk*64 + w*16, +16), full K=4096.
// Round-0 structure (proven fastest: ~41 us, ~5.9 TB/s on the 241 MB stream),
// with the pair-LUT dequant: 256-entry LDS LUT of unscaled bf16 PAIRS
// (index = two 4-bit codes), absmax folded into the per-64k MFMA partial
// (D-row == A-row == output feature), 8 FMAs per 64k block.
// 64 absmax blocks per row (K=4096 / 64).  Direct nontemporal code loads;
// no split-K, no atomics, no extra passes.
__global__ __launch_bounds__(256) void nf4_mfma(
    const int* __restrict__ codes, const float* __restrict__ absmax,
    const unsigned* __restrict__ xB, const float* __restrict__ bias,
    float* __restrict__ out) {
    __shared__ unsigned plut[256];
    plut[threadIdx.x] = pack2(c_nf4[threadIdx.x & 15], c_nf4[threadIdx.x >> 4]);
    __syncthreads();

    const int w  = threadIdx.x >> 6;
    const int l  = threadIdx.x & 63;
    const int o0 = blockIdx.x * 64 + w * 16;
    const int m  = l & 15;
    const int q  = l >> 4;

    const int*   crow = codes + (size_t)(o0 + m) * IN_ + q * 8;
    const uint4* xbp  = (const uint4*)xB + l;
    const float* amp  = absmax + (size_t)(o0 + q * 4) * 64;

    v4f main0 = {0.f, 0.f, 0.f, 0.f};
    v4f main1 = {0.f, 0.f, 0.f, 0.f};
    const v4f zro = {0.f, 0.f, 0.f, 0.f};

#pragma unroll 2
    for (int kb = 0; kb < 64; ++kb) {          // one 64-k absmax block per iter
        const int* cA = crow + (size_t)kb * 64;
        v4i c0 = __builtin_nontemporal_load((const v4i*)(cA));       // step A
        v4i c1 = __builtin_nontemporal_load((const v4i*)(cA + 4));
        v4i c2 = __builtin_nontemporal_load((const v4i*)(cA + 32));  // step B
        v4i c3 = __builtin_nontemporal_load((const v4i*)(cA + 36));
        uint4 b0 = xbp[(size_t)kb * 256];        // step A, b-tile 0
        uint4 b1 = xbp[(size_t)kb * 256 + 64];   // step A, b-tile 1
        uint4 b2 = xbp[(size_t)kb * 256 + 128];  // step B, b-tile 0
        uint4 b3 = xbp[(size_t)kb * 256 + 192];  // step B, b-tile 1
        float am0 = amp[kb];                     // rows o0+q*4 .. +3, block kb
        float am1 = amp[kb + 64];
        float am2 = amp[kb + 128];
        float am3 = amp[kb + 192];

        union { uint4 u; v8s v; } aA, aB, f0, f1, f2, f3;
        aA.u.x = plut[c0.x | (c0.y << 4)];
        aA.u.y = plut[c0.z | (c0.w << 4)];
        aA.u.z = plut[c1.x | (c1.y << 4)];
        aA.u.w = plut[c1.z | (c1.w << 4)];
        aB.u.x = plut[c2.x | (c2.y << 4)];
        aB.u.y = plut[c2.z | (c2.w << 4)];
        aB.u.z = plut[c3.x | (c3.y << 4)];
        aB.u.w = plut[c3.z | (c3.w << 4)];
        f0.u = b0; f1.u = b1; f2.u = b2; f3.u = b3;

        v4f blk0 = __builtin_amdgcn_mfma_f32_16x16x32_bf16(aA.v, f0.v, zro, 0, 0, 0);
        v4f blk1 = __builtin_amdgcn_mfma_f32_16x16x32_bf16(aA.v, f1.v, zro, 0, 0, 0);
        blk0 = __builtin_amdgcn_mfma_f32_16x16x32_bf16(aB.v, f2.v, blk0, 0, 0, 0);
        blk1 = __builtin_amdgcn_mfma_f32_16x16x32_bf16(aB.v, f3.v, blk1, 0, 0, 0);

        main0[0] += am0 * blk0[0];  main1[0] += am0 * blk1[0];
        main0[1] += am1 * blk0[1];  main1[1] += am1 * blk1[1];
        main0[2] += am2 * blk0[2];  main1[2] += am2 * blk1[2];
        main0[3] += am3 * blk0[3];  main1[3] += am3 * blk1[3];
    }

    // D layout: col = l&15 (= batch b within tile), row = q*4 + r (= o offset)
    const int bc = l & 15;
    const int ob = o0 + q * 4;
#pragma unroll
    for (int r = 0; r < 4; ++r) {
        float bv = bias[ob + r];
        out[(size_t)bc * OUT_ + ob + r]        = main0[r] + bv;
        out[(size_t)(bc + 16) * OUT_ + ob + r] = main1[r] + bv;
    }
}

extern "C" void kernel_launch(void* const* d_in, const int* in_sizes, int n_in,
                              void* d_out, int out_size, void* d_ws, size_t ws_size,
                              hipStream_t stream) {
    const float* x      = (const float*)d_in[0];
    const int*   codes  = (const int*)d_in[1];
    const float* absmax = (const float*)d_in[2];
    const float* bias   = (const float*)d_in[3];
    float* out = (float*)d_out;
    unsigned* xB = (unsigned*)d_ws;   // 256 KB

    prep<<<dim3(64), 256, 0, stream>>>(x, xB);
    nf4_mfma<<<dim3(OUT_ / 64), 256, 0, stream>>>(codes, absmax, xB, bias, out);
}

// Round 8
// 326.825 us; speedup vs baseline: 1.0838x; 1.0211x over previous
//
#include <hip/hip_runtime.h>
#include <stddef.h>
#include <stdint.h>

#define B_   32
#define IN_  4096
#define OUT_ 14336

typedef short v8s __attribute__((ext_vector_type(8)));
typedef float v4f __attribute__((ext_vector_type(4)));

__device__ __constant__ float c_nf4[16] = {
    -1.0f, -0.6961928009986877f, -0.5250730514526367f, -0.39491748809814453f,
    -0.28444138169288635f, -0.18477343022823334f, -0.09105003625154495f, 0.0f,
    0.07958029955625534f, 0.16093020141124725f, 0.24611230194568634f,
    0.33791524171829224f, 0.44070982933044434f, 0.5626170039176941f,
    0.7229568362236023f, 1.0f};

__device__ __forceinline__ unsigned f2bf_u(float f) {
    union { float f; unsigned u; } v; v.f = f;
    return (v.u + 0x7FFFu + ((v.u >> 16) & 1u)) >> 16;   // RNE, no NaN inputs
}
__device__ __forceinline__ unsigned pack2(float lo, float hi) {
    return f2bf_u(lo) | (f2bf_u(hi) << 16);
}

// x[32][4096] f32 -> xB bf16 in B-fragment layout for mfma_f32_16x16x32_bf16.
// Fragment t = (kt*2 + bt)*64 + l holds B[k = kt*32 + (l>>4)*8 + j][n = bt*16 + (l&15)]
// at xB uint4-index t (8 bf16 per lane, j = vector element).
__global__ __launch_bounds__(256) void prep(const float* __restrict__ x,
                                            unsigned* __restrict__ xB) {
    int t  = blockIdx.x * 256 + threadIdx.x;   // 0..16383
    int kt = t >> 7;
    int bt = (t >> 6) & 1;
    int l  = t & 63;
    int b  = bt * 16 + (l & 15);
    int k0 = kt * 32 + (l >> 4) * 8;
    const float* xr = x + (size_t)b * IN_ + k0;
    float4 a = *(const float4*)xr;
    float4 c = *(const float4*)(xr + 4);
    uint4 w;
    w.x = pack2(a.x, a.y);
    w.y = pack2(a.z, a.w);
    w.z = pack2(c.x, c.y);
    w.w = pack2(c.z, c.w);
    *(uint4*)(xB + (size_t)t * 4) = w;
}

// Grid 224 x 256. Wave w: o-tile [blk*64 + w*16, +16), full K=4096.
// Per k-step (32 k): A-frag = dequantized codes (lane: row m=l&15, k=q*8+j),
// B-frags from xB (coalesced dwordx4), 2 MFMAs (b-tiles 0,1).
// No LDS writes, no barriers, no manual waitcnt in the K-loop.
// Measured best (322.9 us total window incl. ~280 us harness poison-fills);
// kernel portion ~43 us ~= 89% of the 38.2 us mandatory-traffic roofline.
__global__ __launch_bounds__(256) void nf4_mfma(
    const int* __restrict__ codes, const float* __restrict__ absmax,
    const unsigned* __restrict__ xB, const float* __restrict__ bias,
    float* __restrict__ out) {
    __shared__ float lut[16];
    if (threadIdx.x < 16) lut[threadIdx.x] = c_nf4[threadIdx.x];
    __syncthreads();

    const int w  = threadIdx.x >> 6;
    const int l  = threadIdx.x & 63;
    const int o0 = blockIdx.x * 64 + w * 16;
    const int m  = l & 15;
    const int q  = l >> 4;

    const int*   crow  = codes + (size_t)(o0 + m) * IN_ + q * 8;
    const float* amrow = absmax + (size_t)(o0 + m) * 64;
    const uint4* xbp   = (const uint4*)xB + l;   // + (kt*2+bt)*64

    v4f acc0 = {0.f, 0.f, 0.f, 0.f};
    v4f acc1 = {0.f, 0.f, 0.f, 0.f};

#pragma unroll 4
    for (int kt = 0; kt < 128; ++kt) {
        int4 c0 = *(const int4*)(crow + (size_t)kt * 32);
        int4 c1 = *(const int4*)(crow + (size_t)kt * 32 + 4);
        uint4 b0 = xbp[(size_t)kt * 128];        // b-tile 0
        uint4 b1 = xbp[(size_t)kt * 128 + 64];   // b-tile 1
        float am = amrow[kt >> 1];               // 64-k absmax block

        union { uint4 u; v8s v; } a, f0, f1;
        a.u.x = pack2(lut[c0.x] * am, lut[c0.y] * am);
        a.u.y = pack2(lut[c0.z] * am, lut[c0.w] * am);
        a.u.z = pack2(lut[c1.x] * am, lut[c1.y] * am);
        a.u.w = pack2(lut[c1.z] * am, lut[c1.w] * am);
        f0.u = b0;
        f1.u = b1;
        acc0 = __builtin_amdgcn_mfma_f32_16x16x32_bf16(a.v, f0.v, acc0, 0, 0, 0);
        acc1 = __builtin_amdgcn_mfma_f32_16x16x32_bf16(a.v, f1.v, acc1, 0, 0, 0);
    }

    // D layout: col = l&15 (= b within tile), row = q*4 + r (= o offset)
    const int bc = l & 15;
    const int ob = o0 + q * 4;
#pragma unroll
    for (int r = 0; r < 4; ++r) {
        float bv = bias[ob + r];
        out[(size_t)bc * OUT_ + ob + r]        = acc0[r] + bv;
        out[(size_t)(bc + 16) * OUT_ + ob + r] = acc1[r] + bv;
    }
}

extern "C" void kernel_launch(void* const* d_in, const int* in_sizes, int n_in,
                              void* d_out, int out_size, void* d_ws, size_t ws_size,
                              hipStream_t stream) {
    const float* x      = (const float*)d_in[0];
    const int*   codes  = (const int*)d_in[1];
    const float* absmax = (const float*)d_in[2];
    const float* bias   = (const float*)d_in[3];
    float* out = (float*)d_out;
    unsigned* xB = (unsigned*)d_ws;   // 256 KB (ws known >= 512 KB)

    prep<<<dim3(64), 256, 0, stream>>>(x, xB);
    nf4_mfma<<<dim3(OUT_ / 64), 256, 0, stream>>>(codes, absmax, xB, bias, out);
}